// Round 1
// baseline (334.617 us; speedup 1.0000x reference)
//
#include <hip/hip_runtime.h>
#include <hip/hip_bf16.h>

#define BATCH 8
#define NN    2048
#define DD    64

// -------------------------------------------------------------------------
// Kernel 1: hw = relu(h @ W); t1 = hw @ a1; t2 = hw @ a2
// grid = B*N/64 = 256 blocks, 256 threads. Each block: 64 rows.
// Thread (trow = t>>4, kcol = t&15) computes a 4-row x 4-col register tile.
// -------------------------------------------------------------------------
__global__ __launch_bounds__(256) void k1_hw_t1_t2(
    const float* __restrict__ h, const float* __restrict__ W,
    const float* __restrict__ a1, const float* __restrict__ a2,
    float* __restrict__ hw, float* __restrict__ t1, float* __restrict__ t2) {
  __shared__ float ht[64 * 68];   // h tile transposed: ht[j][i], stride 68 (16B-aligned, conflict-padded)
  __shared__ float Ws[64 * 64];   // W row-major [j][k]

  const int t  = threadIdx.x;
  const int r0 = blockIdx.x * 64; // global flat row base (B*N rows total)

  // load W (shared across blocks, L2-resident): 4096 floats = 1024 float4
#pragma unroll
  for (int r = 0; r < 4; ++r) {
    int f = t + 256 * r;
    reinterpret_cast<float4*>(Ws)[f] = reinterpret_cast<const float4*>(W)[f];
  }
  // load h tile, transpose into LDS
#pragma unroll
  for (int r = 0; r < 4; ++r) {
    int f = t + 256 * r;        // float4 index over 64 rows x 16 chunks
    int i = f >> 4, j4 = f & 15;
    float4 v = reinterpret_cast<const float4*>(h + (size_t)(r0 + i) * DD)[j4];
    ht[(4 * j4 + 0) * 68 + i] = v.x;
    ht[(4 * j4 + 1) * 68 + i] = v.y;
    ht[(4 * j4 + 2) * 68 + i] = v.z;
    ht[(4 * j4 + 3) * 68 + i] = v.w;
  }
  __syncthreads();

  const int trow = t >> 4, kcol = t & 15;
  float4 acc[4];
#pragma unroll
  for (int mi = 0; mi < 4; ++mi) acc[mi] = make_float4(0.f, 0.f, 0.f, 0.f);

#pragma unroll 8
  for (int j = 0; j < 64; ++j) {
    float4 hv = *reinterpret_cast<const float4*>(&ht[j * 68 + 4 * trow]);
    float4 wv = reinterpret_cast<const float4*>(Ws)[j * 16 + kcol];
    acc[0].x = fmaf(hv.x, wv.x, acc[0].x); acc[0].y = fmaf(hv.x, wv.y, acc[0].y);
    acc[0].z = fmaf(hv.x, wv.z, acc[0].z); acc[0].w = fmaf(hv.x, wv.w, acc[0].w);
    acc[1].x = fmaf(hv.y, wv.x, acc[1].x); acc[1].y = fmaf(hv.y, wv.y, acc[1].y);
    acc[1].z = fmaf(hv.y, wv.z, acc[1].z); acc[1].w = fmaf(hv.y, wv.w, acc[1].w);
    acc[2].x = fmaf(hv.z, wv.x, acc[2].x); acc[2].y = fmaf(hv.z, wv.y, acc[2].y);
    acc[2].z = fmaf(hv.z, wv.z, acc[2].z); acc[2].w = fmaf(hv.z, wv.w, acc[2].w);
    acc[3].x = fmaf(hv.w, wv.x, acc[3].x); acc[3].y = fmaf(hv.w, wv.y, acc[3].y);
    acc[3].z = fmaf(hv.w, wv.z, acc[3].z); acc[3].w = fmaf(hv.w, wv.w, acc[3].w);
  }

  // relu, then per-thread partial dots with a1/a2 over this thread's 4 k's
  float4 a1v = reinterpret_cast<const float4*>(a1)[kcol];
  float4 a2v = reinterpret_cast<const float4*>(a2)[kcol];
  float s1[4], s2[4];
#pragma unroll
  for (int mi = 0; mi < 4; ++mi) {
    acc[mi].x = fmaxf(acc[mi].x, 0.f); acc[mi].y = fmaxf(acc[mi].y, 0.f);
    acc[mi].z = fmaxf(acc[mi].z, 0.f); acc[mi].w = fmaxf(acc[mi].w, 0.f);
    s1[mi] = acc[mi].x * a1v.x + acc[mi].y * a1v.y + acc[mi].z * a1v.z + acc[mi].w * a1v.w;
    s2[mi] = acc[mi].x * a2v.x + acc[mi].y * a2v.y + acc[mi].z * a2v.z + acc[mi].w * a2v.w;
  }
  // butterfly over the 16 kcol lanes (masks 1,2,4,8 stay within kcol bits -> within wave)
#pragma unroll
  for (int m = 1; m <= 8; m <<= 1) {
#pragma unroll
    for (int mi = 0; mi < 4; ++mi) {
      s1[mi] += __shfl_xor(s1[mi], m, 64);
      s2[mi] += __shfl_xor(s2[mi], m, 64);
    }
  }
#pragma unroll
  for (int mi = 0; mi < 4; ++mi) {
    int row = r0 + 4 * trow + mi;
    reinterpret_cast<float4*>(hw + (size_t)row * DD)[kcol] = acc[mi];
    if (kcol == 0) { t1[row] = s1[mi]; t2[row] = s2[mi]; }
  }
}

// -------------------------------------------------------------------------
// Kernel 2: fused masked-softmax attention + aggregation + root select.
// p_ij = adj ? exp(relu(t1_i + t2_j)) : 1   (no max-subtract needed: |t|<~5)
// out_i = h_root_i > 0 ? (sum_j p_ij hw_j) / (sum_j p_ij) : h0_i
// grid = B * (N/64) = 256 blocks, 256 threads, 32 j-tiles of 64.
// -------------------------------------------------------------------------
__global__ __launch_bounds__(256) void k2_attn(
    const float* __restrict__ hw, const int* __restrict__ adj,
    const float* __restrict__ t1, const float* __restrict__ t2,
    const float* __restrict__ h, const float* __restrict__ h_root,
    float* __restrict__ out) {
  __shared__ float Pt[64 * 68];   // P transposed: Pt[j][i], stride 68
  __shared__ float hws[64 * 64];  // hw tile: [j][k]
  __shared__ float t1s[64];

  const int t  = threadIdx.x;
  const int b  = blockIdx.x >> 5;
  const int i0 = (blockIdx.x & 31) * 64;
  const size_t rowbase = (size_t)b * NN + i0;

  if (t < 64) t1s[t] = t1[rowbase + t];

  const int trow = t >> 4, kcol = t & 15;  // phase-2 tile coords
  const int j4 = kcol;                     // phase-1: 4 consecutive j's
  const int irow = trow;                   // phase-1: i = irow + 16*r

  float4 acc[4];
  float  den[4];
#pragma unroll
  for (int mi = 0; mi < 4; ++mi) { acc[mi] = make_float4(0.f, 0.f, 0.f, 0.f); den[mi] = 0.f; }

  const float* hwb  = hw + (size_t)b * NN * DD;
  const int*   adjb = adj + (size_t)(b * NN + i0) * NN;
  const float* t2b  = t2 + (size_t)b * NN;

  int4   adjv[4];
  float4 hwv[4];
  float4 t2v;

  auto prefetch = [&](int jt) {
    const int j0 = jt * 64;
    t2v = *reinterpret_cast<const float4*>(t2b + j0 + 4 * j4);
#pragma unroll
    for (int r = 0; r < 4; ++r) {
      hwv[r]  = reinterpret_cast<const float4*>(hwb + (size_t)j0 * DD)[t + 256 * r];
      adjv[r] = *reinterpret_cast<const int4*>(adjb + (size_t)(irow + 16 * r) * NN + j0 + 4 * j4);
    }
  };
  prefetch(0);
  __syncthreads();  // t1s ready

  for (int jt = 0; jt < 32; ++jt) {
    // stage hw tile (from prefetched regs)
#pragma unroll
    for (int r = 0; r < 4; ++r)
      reinterpret_cast<float4*>(hws)[t + 256 * r] = hwv[r];

    // phase 1: P tile into LDS (transposed)
#pragma unroll
    for (int r = 0; r < 4; ++r) {
      const int i = irow + 16 * r;
      const float t1v = t1s[i];
      const int4 av = adjv[r];
      Pt[(4 * j4 + 0) * 68 + i] = (av.x > 0) ? __expf(fmaxf(t1v + t2v.x, 0.f)) : 1.f;
      Pt[(4 * j4 + 1) * 68 + i] = (av.y > 0) ? __expf(fmaxf(t1v + t2v.y, 0.f)) : 1.f;
      Pt[(4 * j4 + 2) * 68 + i] = (av.z > 0) ? __expf(fmaxf(t1v + t2v.z, 0.f)) : 1.f;
      Pt[(4 * j4 + 3) * 68 + i] = (av.w > 0) ? __expf(fmaxf(t1v + t2v.w, 0.f)) : 1.f;
    }
    __syncthreads();

    // prefetch next tile (overlaps with phase-2 compute)
    if (jt + 1 < 32) prefetch(jt + 1);

    // phase 2: acc[i-tile 4][k-tile 4] += P^T @ hw
#pragma unroll 8
    for (int j = 0; j < 64; ++j) {
      float4 p4 = *reinterpret_cast<const float4*>(&Pt[j * 68 + 4 * trow]);
      float4 hv = reinterpret_cast<const float4*>(hws)[j * 16 + kcol];
      acc[0].x = fmaf(p4.x, hv.x, acc[0].x); acc[0].y = fmaf(p4.x, hv.y, acc[0].y);
      acc[0].z = fmaf(p4.x, hv.z, acc[0].z); acc[0].w = fmaf(p4.x, hv.w, acc[0].w);
      den[0] += p4.x;
      acc[1].x = fmaf(p4.y, hv.x, acc[1].x); acc[1].y = fmaf(p4.y, hv.y, acc[1].y);
      acc[1].z = fmaf(p4.y, hv.z, acc[1].z); acc[1].w = fmaf(p4.y, hv.w, acc[1].w);
      den[1] += p4.y;
      acc[2].x = fmaf(p4.z, hv.x, acc[2].x); acc[2].y = fmaf(p4.z, hv.y, acc[2].y);
      acc[2].z = fmaf(p4.z, hv.z, acc[2].z); acc[2].w = fmaf(p4.z, hv.w, acc[2].w);
      den[2] += p4.z;
      acc[3].x = fmaf(p4.w, hv.x, acc[3].x); acc[3].y = fmaf(p4.w, hv.y, acc[3].y);
      acc[3].z = fmaf(p4.w, hv.z, acc[3].z); acc[3].w = fmaf(p4.w, hv.w, acc[3].w);
      den[3] += p4.w;
    }
    __syncthreads();
  }

  // epilogue: normalize + root-select + store
#pragma unroll
  for (int mi = 0; mi < 4; ++mi) {
    const size_t row = rowbase + 4 * trow + mi;
    const float hr = h_root[row];
    float4 res;
    if (hr > 0.f) {
      const float inv = 1.f / den[mi];
      res.x = acc[mi].x * inv; res.y = acc[mi].y * inv;
      res.z = acc[mi].z * inv; res.w = acc[mi].w * inv;
    } else {
      res = reinterpret_cast<const float4*>(h + row * DD)[kcol];
    }
    reinterpret_cast<float4*>(out + row * DD)[kcol] = res;
  }
}

extern "C" void kernel_launch(void* const* d_in, const int* in_sizes, int n_in,
                              void* d_out, int out_size, void* d_ws, size_t ws_size,
                              hipStream_t stream) {
  const float* h      = (const float*)d_in[0];
  const int*   adj    = (const int*)d_in[1];
  const float* h_root = (const float*)d_in[2];
  const float* W      = (const float*)d_in[3];
  const float* a1     = (const float*)d_in[4];
  const float* a2     = (const float*)d_in[5];
  float* out = (float*)d_out;

  float* wsf = (float*)d_ws;
  float* hw = wsf;                                  // B*N*D floats = 4 MB
  float* t1 = wsf + (size_t)BATCH * NN * DD;        // B*N floats
  float* t2 = t1 + (size_t)BATCH * NN;              // B*N floats

  k1_hw_t1_t2<<<BATCH * NN / 64, 256, 0, stream>>>(h, W, a1, a2, hw, t1, t2);
  k2_attn<<<BATCH * (NN / 64), 256, 0, stream>>>(hw, adj, t1, t2, h, h_root, out);
}

// Round 2
// 264.175 us; speedup vs baseline: 1.2666x; 1.2666x over previous
//
#include <hip/hip_runtime.h>
#include <hip/hip_bf16.h>

#define BATCH 8
#define NN    2048
#define DD    64
#define BN    (BATCH * NN)          // 16384 rows

// -------------------------------------------------------------------------
// Kernel 1: hw = relu(h @ W); t1 = hw @ a1; t2 = hw @ a2
// grid = B*N/32 = 512 blocks (2 blocks/CU), 256 threads, 32 rows/block.
// Thread (trow = t>>4, kcol = t&15) computes a 2-row x 4-col register tile.
// -------------------------------------------------------------------------
__global__ __launch_bounds__(256) void k1_hw_t1_t2(
    const float* __restrict__ h, const float* __restrict__ W,
    const float* __restrict__ a1, const float* __restrict__ a2,
    float* __restrict__ hw, float* __restrict__ t1, float* __restrict__ t2) {
  __shared__ float ht[64 * 36];   // h tile transposed: ht[j][i], i<32, stride 36
  __shared__ float Ws[64 * 64];   // W row-major [j][k]

  const int t  = threadIdx.x;
  const int r0 = blockIdx.x * 32; // global flat row base (B*N rows total)

#pragma unroll
  for (int r = 0; r < 4; ++r) {
    int f = t + 256 * r;
    reinterpret_cast<float4*>(Ws)[f] = reinterpret_cast<const float4*>(W)[f];
  }
#pragma unroll
  for (int r = 0; r < 2; ++r) {
    int f = t + 256 * r;        // float4 index over 32 rows x 16 chunks
    int i = f >> 4, j4 = f & 15;
    float4 v = reinterpret_cast<const float4*>(h + (size_t)(r0 + i) * DD)[j4];
    ht[(4 * j4 + 0) * 36 + i] = v.x;
    ht[(4 * j4 + 1) * 36 + i] = v.y;
    ht[(4 * j4 + 2) * 36 + i] = v.z;
    ht[(4 * j4 + 3) * 36 + i] = v.w;
  }
  __syncthreads();

  const int trow = t >> 4, kcol = t & 15;
  float4 acc0 = make_float4(0.f, 0.f, 0.f, 0.f);
  float4 acc1 = make_float4(0.f, 0.f, 0.f, 0.f);

#pragma unroll 8
  for (int j = 0; j < 64; ++j) {
    float2 hv = *reinterpret_cast<const float2*>(&ht[j * 36 + 2 * trow]);
    float4 wv = reinterpret_cast<const float4*>(Ws)[j * 16 + kcol];
    acc0.x = fmaf(hv.x, wv.x, acc0.x); acc0.y = fmaf(hv.x, wv.y, acc0.y);
    acc0.z = fmaf(hv.x, wv.z, acc0.z); acc0.w = fmaf(hv.x, wv.w, acc0.w);
    acc1.x = fmaf(hv.y, wv.x, acc1.x); acc1.y = fmaf(hv.y, wv.y, acc1.y);
    acc1.z = fmaf(hv.y, wv.z, acc1.z); acc1.w = fmaf(hv.y, wv.w, acc1.w);
  }

  acc0.x = fmaxf(acc0.x, 0.f); acc0.y = fmaxf(acc0.y, 0.f);
  acc0.z = fmaxf(acc0.z, 0.f); acc0.w = fmaxf(acc0.w, 0.f);
  acc1.x = fmaxf(acc1.x, 0.f); acc1.y = fmaxf(acc1.y, 0.f);
  acc1.z = fmaxf(acc1.z, 0.f); acc1.w = fmaxf(acc1.w, 0.f);

  float4 a1v = reinterpret_cast<const float4*>(a1)[kcol];
  float4 a2v = reinterpret_cast<const float4*>(a2)[kcol];
  float s1_0 = acc0.x * a1v.x + acc0.y * a1v.y + acc0.z * a1v.z + acc0.w * a1v.w;
  float s1_1 = acc1.x * a1v.x + acc1.y * a1v.y + acc1.z * a1v.z + acc1.w * a1v.w;
  float s2_0 = acc0.x * a2v.x + acc0.y * a2v.y + acc0.z * a2v.z + acc0.w * a2v.w;
  float s2_1 = acc1.x * a2v.x + acc1.y * a2v.y + acc1.z * a2v.z + acc1.w * a2v.w;
#pragma unroll
  for (int m = 1; m <= 8; m <<= 1) {
    s1_0 += __shfl_xor(s1_0, m, 64);
    s1_1 += __shfl_xor(s1_1, m, 64);
    s2_0 += __shfl_xor(s2_0, m, 64);
    s2_1 += __shfl_xor(s2_1, m, 64);
  }
  {
    int row = r0 + 2 * trow;
    reinterpret_cast<float4*>(hw + (size_t)row * DD)[kcol] = acc0;
    reinterpret_cast<float4*>(hw + (size_t)(row + 1) * DD)[kcol] = acc1;
    if (kcol == 0) {
      t1[row] = s1_0; t1[row + 1] = s1_1;
      t2[row] = s2_0; t2[row + 1] = s2_1;
    }
  }
}

// -------------------------------------------------------------------------
// Kernel 2: fused masked-softmax attention, j-split into `nsplit` partials.
// p_ij = adj ? exp(relu(t1_i + t2_j)) : 1   (|t1+t2| small -> no max-sub)
// Each block: one (batch, 64-row i-tile, j-split). Writes partial
// acc (64x64) and den (64) to workspace.
// grid = nsplit * B * (N/64) = nsplit*256 blocks, 256 threads.
// -------------------------------------------------------------------------
__global__ __launch_bounds__(256) void k2_attn_split(
    const float* __restrict__ hw, const int* __restrict__ adj,
    const float* __restrict__ t1, const float* __restrict__ t2,
    float* __restrict__ pacc, float* __restrict__ pden, int tiles_per_split) {
  __shared__ float Pt[64 * 68];   // P transposed: Pt[j][i], stride 68
  __shared__ float hws[64 * 64];  // hw tile: [j][k]
  __shared__ float t1s[64];

  const int t     = threadIdx.x;
  const int split = blockIdx.x >> 8;
  const int rem   = blockIdx.x & 255;
  const int b     = rem >> 5;
  const int i0    = (rem & 31) * 64;
  const size_t rowbase = (size_t)b * NN + i0;

  if (t < 64) t1s[t] = t1[rowbase + t];

  const int trow = t >> 4, kcol = t & 15;  // phase-2 tile coords
  const int j4 = kcol;                     // phase-1: 4 consecutive j's
  const int irow = trow;                   // phase-1: i = irow + 16*r

  float4 acc[4];
  float  den[4];
#pragma unroll
  for (int mi = 0; mi < 4; ++mi) { acc[mi] = make_float4(0.f, 0.f, 0.f, 0.f); den[mi] = 0.f; }

  const float* hwb  = hw + (size_t)b * NN * DD;
  const int*   adjb = adj + (size_t)(b * NN + i0) * NN;
  const float* t2b  = t2 + (size_t)b * NN;

  const int jt0 = split * tiles_per_split;

  int4   adjv[4];
  float4 hwv[4];
  float4 t2v;

  auto prefetch = [&](int jt) {
    const int j0 = jt * 64;
    t2v = *reinterpret_cast<const float4*>(t2b + j0 + 4 * j4);
#pragma unroll
    for (int r = 0; r < 4; ++r) {
      hwv[r]  = reinterpret_cast<const float4*>(hwb + (size_t)j0 * DD)[t + 256 * r];
      adjv[r] = *reinterpret_cast<const int4*>(adjb + (size_t)(irow + 16 * r) * NN + j0 + 4 * j4);
    }
  };
  prefetch(jt0);
  __syncthreads();  // t1s ready

  for (int lt = 0; lt < tiles_per_split; ++lt) {
    // stage hw tile (from prefetched regs)
#pragma unroll
    for (int r = 0; r < 4; ++r)
      reinterpret_cast<float4*>(hws)[t + 256 * r] = hwv[r];

    // phase 1: P tile into LDS (transposed)
#pragma unroll
    for (int r = 0; r < 4; ++r) {
      const int i = irow + 16 * r;
      const float t1v = t1s[i];
      const int4 av = adjv[r];
      Pt[(4 * j4 + 0) * 68 + i] = (av.x > 0) ? __expf(fmaxf(t1v + t2v.x, 0.f)) : 1.f;
      Pt[(4 * j4 + 1) * 68 + i] = (av.y > 0) ? __expf(fmaxf(t1v + t2v.y, 0.f)) : 1.f;
      Pt[(4 * j4 + 2) * 68 + i] = (av.z > 0) ? __expf(fmaxf(t1v + t2v.z, 0.f)) : 1.f;
      Pt[(4 * j4 + 3) * 68 + i] = (av.w > 0) ? __expf(fmaxf(t1v + t2v.w, 0.f)) : 1.f;
    }
    __syncthreads();

    // prefetch next tile (overlaps with phase-2 compute)
    if (lt + 1 < tiles_per_split) prefetch(jt0 + lt + 1);

    // phase 2: acc[i-tile 4][k-tile 4] += P^T @ hw
#pragma unroll 8
    for (int j = 0; j < 64; ++j) {
      float4 p4 = *reinterpret_cast<const float4*>(&Pt[j * 68 + 4 * trow]);
      float4 hv = reinterpret_cast<const float4*>(hws)[j * 16 + kcol];
      acc[0].x = fmaf(p4.x, hv.x, acc[0].x); acc[0].y = fmaf(p4.x, hv.y, acc[0].y);
      acc[0].z = fmaf(p4.x, hv.z, acc[0].z); acc[0].w = fmaf(p4.x, hv.w, acc[0].w);
      den[0] += p4.x;
      acc[1].x = fmaf(p4.y, hv.x, acc[1].x); acc[1].y = fmaf(p4.y, hv.y, acc[1].y);
      acc[1].z = fmaf(p4.y, hv.z, acc[1].z); acc[1].w = fmaf(p4.y, hv.w, acc[1].w);
      den[1] += p4.y;
      acc[2].x = fmaf(p4.z, hv.x, acc[2].x); acc[2].y = fmaf(p4.z, hv.y, acc[2].y);
      acc[2].z = fmaf(p4.z, hv.z, acc[2].z); acc[2].w = fmaf(p4.z, hv.w, acc[2].w);
      den[2] += p4.z;
      acc[3].x = fmaf(p4.w, hv.x, acc[3].x); acc[3].y = fmaf(p4.w, hv.y, acc[3].y);
      acc[3].z = fmaf(p4.w, hv.z, acc[3].z); acc[3].w = fmaf(p4.w, hv.w, acc[3].w);
      den[3] += p4.w;
    }
    __syncthreads();
  }

  // write partials
#pragma unroll
  for (int mi = 0; mi < 4; ++mi) {
    const size_t prow = (size_t)split * BN + rowbase + 4 * trow + mi;
    reinterpret_cast<float4*>(pacc + prow * DD)[kcol] = acc[mi];
    if (kcol == 0) pden[prow] = den[mi];
  }
}

// -------------------------------------------------------------------------
// Kernel 3: reduce partials + normalize + root-select + store.
// grid = B*N*D/4/256 = 1024 blocks, 256 threads, one float4/thread.
// -------------------------------------------------------------------------
__global__ __launch_bounds__(256) void k3_reduce(
    const float* __restrict__ pacc, const float* __restrict__ pden,
    const float* __restrict__ h, const float* __restrict__ h_root,
    float* __restrict__ out, int nsplit) {
  const int g   = blockIdx.x * 256 + threadIdx.x;  // float4 index
  const int row = g >> 4;
  const int k4  = g & 15;

  float4 a = make_float4(0.f, 0.f, 0.f, 0.f);
  float den = 0.f;
  for (int s = 0; s < nsplit; ++s) {
    const size_t prow = (size_t)s * BN + row;
    float4 p = reinterpret_cast<const float4*>(pacc + prow * DD)[k4];
    a.x += p.x; a.y += p.y; a.z += p.z; a.w += p.w;
    den += pden[prow];
  }
  const float hr = h_root[row];
  float4 res;
  if (hr > 0.f) {
    const float inv = 1.f / den;
    res.x = a.x * inv; res.y = a.y * inv; res.z = a.z * inv; res.w = a.w * inv;
  } else {
    res = reinterpret_cast<const float4*>(h)[g];
  }
  reinterpret_cast<float4*>(out)[g] = res;
}

extern "C" void kernel_launch(void* const* d_in, const int* in_sizes, int n_in,
                              void* d_out, int out_size, void* d_ws, size_t ws_size,
                              hipStream_t stream) {
  const float* h      = (const float*)d_in[0];
  const int*   adj    = (const int*)d_in[1];
  const float* h_root = (const float*)d_in[2];
  const float* W      = (const float*)d_in[3];
  const float* a1     = (const float*)d_in[4];
  const float* a2     = (const float*)d_in[5];
  float* out = (float*)d_out;

  // workspace layout (floats): hw | t1 | t2 | pacc[nsplit] | pden[nsplit]
  float* wsf = (float*)d_ws;
  float* hw = wsf;
  float* t1 = hw + (size_t)BN * DD;
  float* t2 = t1 + BN;
  float* pacc = t2 + BN;

  // pick largest nsplit that fits the workspace
  int nsplit = 4;
  while (nsplit > 1) {
    size_t need = sizeof(float) * ((size_t)BN * DD + 2 * BN +
                                   (size_t)nsplit * ((size_t)BN * DD + BN));
    if (need <= ws_size) break;
    nsplit >>= 1;
  }
  float* pden = pacc + (size_t)nsplit * BN * DD;

  k1_hw_t1_t2<<<BN / 32, 256, 0, stream>>>(h, W, a1, a2, hw, t1, t2);
  k2_attn_split<<<nsplit * 256, 256, 0, stream>>>(hw, adj, t1, t2, pacc, pden,
                                                  32 / nsplit);
  k3_reduce<<<(BN * DD / 4) / 256, 256, 0, stream>>>(pacc, pden, h, h_root, out,
                                                     nsplit);
}

// Round 3
// 222.542 us; speedup vs baseline: 1.5036x; 1.1871x over previous
//
#include <hip/hip_runtime.h>
#include <hip/hip_bf16.h>

#define BATCH 8
#define NN    2048
#define DD    64
#define BN    (BATCH * NN)          // 16384 rows

typedef __attribute__((ext_vector_type(8))) short bf16x8;
typedef __attribute__((ext_vector_type(4))) float f32x4;

// pack two fp32 into one dword of two RNE-rounded bf16 (lo, hi)
static __device__ __forceinline__ unsigned f2bf_pk(float lo, float hi) {
  unsigned ul = __float_as_uint(lo);
  unsigned uh = __float_as_uint(hi);
  ul = (ul + 0x7fffu + ((ul >> 16) & 1u)) >> 16;
  uh = (uh + 0x7fffu + ((uh >> 16) & 1u)) & 0xffff0000u;
  return ul | uh;
}

// -------------------------------------------------------------------------
// Kernel 1: hw = relu(h @ W); t1 = hw@a1; t2 = hw@a2; hwT = bf16 hw^T [b][k][j]
// grid = BN/32 = 512 blocks, 256 threads, 32 rows/block.
// -------------------------------------------------------------------------
__global__ __launch_bounds__(256) void k1_hw_t1_t2(
    const float* __restrict__ h, const float* __restrict__ W,
    const float* __restrict__ a1, const float* __restrict__ a2,
    unsigned short* __restrict__ hwT, float* __restrict__ t1, float* __restrict__ t2) {
  __shared__ float ht[64 * 36];          // h tile transposed [j][i<32], stride 36
  __shared__ float Ws[64 * 64];          // W row-major [j][k]
  __shared__ unsigned short bt[64 * 40]; // bf16 bounce [k][j<32], stride 40 (16B-aligned rows)

  const int t  = threadIdx.x;
  const int r0 = blockIdx.x * 32;

#pragma unroll
  for (int r = 0; r < 4; ++r) {
    int f = t + 256 * r;
    reinterpret_cast<float4*>(Ws)[f] = reinterpret_cast<const float4*>(W)[f];
  }
#pragma unroll
  for (int r = 0; r < 2; ++r) {
    int f = t + 256 * r;
    int i = f >> 4, j4 = f & 15;
    float4 v = reinterpret_cast<const float4*>(h + (size_t)(r0 + i) * DD)[j4];
    ht[(4 * j4 + 0) * 36 + i] = v.x;
    ht[(4 * j4 + 1) * 36 + i] = v.y;
    ht[(4 * j4 + 2) * 36 + i] = v.z;
    ht[(4 * j4 + 3) * 36 + i] = v.w;
  }
  __syncthreads();

  const int trow = t >> 4, kcol = t & 15;
  float4 acc0 = make_float4(0.f, 0.f, 0.f, 0.f);
  float4 acc1 = make_float4(0.f, 0.f, 0.f, 0.f);

#pragma unroll 8
  for (int j = 0; j < 64; ++j) {
    float2 hv = *reinterpret_cast<const float2*>(&ht[j * 36 + 2 * trow]);
    float4 wv = reinterpret_cast<const float4*>(Ws)[j * 16 + kcol];
    acc0.x = fmaf(hv.x, wv.x, acc0.x); acc0.y = fmaf(hv.x, wv.y, acc0.y);
    acc0.z = fmaf(hv.x, wv.z, acc0.z); acc0.w = fmaf(hv.x, wv.w, acc0.w);
    acc1.x = fmaf(hv.y, wv.x, acc1.x); acc1.y = fmaf(hv.y, wv.y, acc1.y);
    acc1.z = fmaf(hv.y, wv.z, acc1.z); acc1.w = fmaf(hv.y, wv.w, acc1.w);
  }

  acc0.x = fmaxf(acc0.x, 0.f); acc0.y = fmaxf(acc0.y, 0.f);
  acc0.z = fmaxf(acc0.z, 0.f); acc0.w = fmaxf(acc0.w, 0.f);
  acc1.x = fmaxf(acc1.x, 0.f); acc1.y = fmaxf(acc1.y, 0.f);
  acc1.z = fmaxf(acc1.z, 0.f); acc1.w = fmaxf(acc1.w, 0.f);

  // t1/t2 partial dots + in-wave butterfly over kcol (lane bits 0..3)
  float4 a1v = reinterpret_cast<const float4*>(a1)[kcol];
  float4 a2v = reinterpret_cast<const float4*>(a2)[kcol];
  float s1_0 = acc0.x * a1v.x + acc0.y * a1v.y + acc0.z * a1v.z + acc0.w * a1v.w;
  float s1_1 = acc1.x * a1v.x + acc1.y * a1v.y + acc1.z * a1v.z + acc1.w * a1v.w;
  float s2_0 = acc0.x * a2v.x + acc0.y * a2v.y + acc0.z * a2v.z + acc0.w * a2v.w;
  float s2_1 = acc1.x * a2v.x + acc1.y * a2v.y + acc1.z * a2v.z + acc1.w * a2v.w;
#pragma unroll
  for (int m = 1; m <= 8; m <<= 1) {
    s1_0 += __shfl_xor(s1_0, m, 64);
    s1_1 += __shfl_xor(s1_1, m, 64);
    s2_0 += __shfl_xor(s2_0, m, 64);
    s2_1 += __shfl_xor(s2_1, m, 64);
  }
  {
    int row = r0 + 2 * trow;
    if (kcol == 0) {
      t1[row] = s1_0; t1[row + 1] = s1_1;
      t2[row] = s2_0; t2[row + 1] = s2_1;
    }
  }

  // bounce bf16 transposed tile through LDS, then coalesced copy-out
  {
    const float* a0 = &acc0.x;
    const float* a1p = &acc1.x;
#pragma unroll
    for (int c = 0; c < 4; ++c) {
      int k = 4 * kcol + c;
      *reinterpret_cast<unsigned*>(&bt[k * 40 + 2 * trow]) = f2bf_pk(a0[c], a1p[c]);
    }
  }
  __syncthreads();
  {
    int k = t >> 2, jp = t & 3;
    int bb = r0 >> 11;          // batch
    int jb = r0 & (NN - 1);     // j base within batch
    *reinterpret_cast<int4*>(hwT + ((size_t)bb * DD + k) * NN + jb + jp * 8) =
        *reinterpret_cast<const int4*>(&bt[k * 40 + jp * 8]);
  }
}

// -------------------------------------------------------------------------
// Kernel 2: MFMA attention. P generated in registers in A-frag layout:
//   lane m=lane&15 owns row i = i0+w*16+m; quad=lane>>4 owns j = j0+quad*8+jj.
//   p = adj ? exp(relu(t1_i + t2_j)) : 1
// B-frag = bf16 hwT chunk staged in LDS (padded stride), ds_read_b128.
// acc: 4 frags (16x64 per wave). den accumulated in fp32, quad-reduced.
// grid = nsplit*256 blocks (one (split,b,i-tile) each), 256 threads.
// -------------------------------------------------------------------------
#define JCHUNK 128
#define LDST   136   // padded LDS stride in ushorts (272 B, 16B-aligned rows)

__global__ __launch_bounds__(256, 2) void k2_attn(
    const unsigned short* __restrict__ hwT, const int* __restrict__ adj,
    const float* __restrict__ t1, const float* __restrict__ t2,
    float* __restrict__ pacc, float* __restrict__ pden, int nsplit) {
  __shared__ unsigned short hws[2][64 * LDST];
  __shared__ float t2s[2][JCHUNK];

  const int t     = threadIdx.x;
  const int split = blockIdx.x >> 8;
  const int rem   = blockIdx.x & 255;
  const int b     = rem >> 5;
  const int i0    = (rem & 31) * 64;
  const int w     = t >> 6;
  const int lane  = t & 63;
  const int m     = lane & 15;
  const int quad  = lane >> 4;

  const int jspan  = NN / nsplit;
  const int jbase  = split * jspan;
  const int chunks = jspan / JCHUNK;

  const float t1v = t1[b * NN + i0 + w * 16 + m];
  const int*  adjl = adj + (size_t)(b * NN + i0 + w * 16 + m) * NN + jbase + quad * 8;
  const unsigned short* hwTb = hwT + (size_t)b * DD * NN;
  const float* t2b = t2 + b * NN + jbase;

  f32x4 acc[4];
#pragma unroll
  for (int g = 0; g < 4; ++g) acc[g] = (f32x4){0.f, 0.f, 0.f, 0.f};
  float den = 0.f;

  int4   sreg[4];
  float4 t2reg;
  int4   adjv[8], adjn[8];

  auto stage_load = [&](int c) {
    const unsigned short* src = hwTb + jbase + c * JCHUNK;
#pragma unroll
    for (int r = 0; r < 4; ++r) {
      int idx = t + 256 * r, k = idx >> 4, jp = idx & 15;
      sreg[r] = *reinterpret_cast<const int4*>(src + (size_t)k * NN + jp * 8);
    }
    if (t < 32) t2reg = *reinterpret_cast<const float4*>(t2b + c * JCHUNK + t * 4);
  };
  auto stage_write = [&](int buf) {
#pragma unroll
    for (int r = 0; r < 4; ++r) {
      int idx = t + 256 * r, k = idx >> 4, jp = idx & 15;
      *reinterpret_cast<int4*>(&hws[buf][k * LDST + jp * 8]) = sreg[r];
    }
    if (t < 32) *reinterpret_cast<float4*>(&t2s[buf][t * 4]) = t2reg;
  };
  auto load_adj = [&](int c, int4* dst) {
    const int* ap = adjl + c * JCHUNK;
#pragma unroll
    for (int ks = 0; ks < 4; ++ks) {
      dst[2 * ks]     = *reinterpret_cast<const int4*>(ap + ks * 32);
      dst[2 * ks + 1] = *reinterpret_cast<const int4*>(ap + ks * 32 + 4);
    }
  };

  load_adj(0, adjv);
  stage_load(0);
  stage_write(0);
  __syncthreads();

  int buf = 0;
  for (int c = 0; c < chunks; ++c) {
    if (c + 1 < chunks) { stage_load(c + 1); load_adj(c + 1, adjn); }

#pragma unroll
    for (int ks = 0; ks < 4; ++ks) {
      float4 e0 = *reinterpret_cast<const float4*>(&t2s[buf][ks * 32 + quad * 8]);
      float4 e1 = *reinterpret_cast<const float4*>(&t2s[buf][ks * 32 + quad * 8 + 4]);
      int4 A0 = adjv[2 * ks], A1 = adjv[2 * ks + 1];
      float p0 = (A0.x > 0) ? __expf(fmaxf(t1v + e0.x, 0.f)) : 1.f;
      float p1 = (A0.y > 0) ? __expf(fmaxf(t1v + e0.y, 0.f)) : 1.f;
      float p2 = (A0.z > 0) ? __expf(fmaxf(t1v + e0.z, 0.f)) : 1.f;
      float p3 = (A0.w > 0) ? __expf(fmaxf(t1v + e0.w, 0.f)) : 1.f;
      float p4 = (A1.x > 0) ? __expf(fmaxf(t1v + e1.x, 0.f)) : 1.f;
      float p5 = (A1.y > 0) ? __expf(fmaxf(t1v + e1.y, 0.f)) : 1.f;
      float p6 = (A1.z > 0) ? __expf(fmaxf(t1v + e1.z, 0.f)) : 1.f;
      float p7 = (A1.w > 0) ? __expf(fmaxf(t1v + e1.w, 0.f)) : 1.f;
      den += ((p0 + p1) + (p2 + p3)) + ((p4 + p5) + (p6 + p7));

      union { bf16x8 v; unsigned u[4]; } Af;
      Af.u[0] = f2bf_pk(p0, p1);
      Af.u[1] = f2bf_pk(p2, p3);
      Af.u[2] = f2bf_pk(p4, p5);
      Af.u[3] = f2bf_pk(p6, p7);

#pragma unroll
      for (int g = 0; g < 4; ++g) {
        bf16x8 Bf = *reinterpret_cast<const bf16x8*>(
            &hws[buf][(g * 16 + m) * LDST + ks * 32 + quad * 8]);
        acc[g] = __builtin_amdgcn_mfma_f32_16x16x32_bf16(Af.v, Bf, acc[g], 0, 0, 0);
      }
    }

    if (c + 1 < chunks) {
      stage_write(buf ^ 1);
#pragma unroll
      for (int r = 0; r < 8; ++r) adjv[r] = adjn[r];
    }
    __syncthreads();
    buf ^= 1;
  }

  // den: reduce over quads (each quad summed its own j subset)
  den += __shfl_xor(den, 16, 64);
  den += __shfl_xor(den, 32, 64);

  const size_t obase = (size_t)split * BN + (size_t)b * NN + i0 + w * 16;
  if (quad == 0) pden[obase + m] = den;
#pragma unroll
  for (int g = 0; g < 4; ++g)
#pragma unroll
    for (int r = 0; r < 4; ++r)
      pacc[(obase + quad * 4 + r) * DD + g * 16 + m] = acc[g][r];
}

// -------------------------------------------------------------------------
// Kernel 3: reduce partials + normalize + root-select + store.
// -------------------------------------------------------------------------
__global__ __launch_bounds__(256) void k3_reduce(
    const float* __restrict__ pacc, const float* __restrict__ pden,
    const float* __restrict__ h, const float* __restrict__ h_root,
    float* __restrict__ out, int nsplit) {
  const int g   = blockIdx.x * 256 + threadIdx.x;  // float4 index
  const int row = g >> 4;
  const int k4  = g & 15;

  float4 a = make_float4(0.f, 0.f, 0.f, 0.f);
  float den = 0.f;
  for (int s = 0; s < nsplit; ++s) {
    const size_t prow = (size_t)s * BN + row;
    float4 p = reinterpret_cast<const float4*>(pacc + prow * DD)[k4];
    a.x += p.x; a.y += p.y; a.z += p.z; a.w += p.w;
    den += pden[prow];
  }
  const float hr = h_root[row];
  float4 res;
  if (hr > 0.f) {
    const float inv = 1.f / den;
    res.x = a.x * inv; res.y = a.y * inv; res.z = a.z * inv; res.w = a.w * inv;
  } else {
    res = reinterpret_cast<const float4*>(h)[g];
  }
  reinterpret_cast<float4*>(out)[g] = res;
}

extern "C" void kernel_launch(void* const* d_in, const int* in_sizes, int n_in,
                              void* d_out, int out_size, void* d_ws, size_t ws_size,
                              hipStream_t stream) {
  const float* h      = (const float*)d_in[0];
  const int*   adj    = (const int*)d_in[1];
  const float* h_root = (const float*)d_in[2];
  const float* W      = (const float*)d_in[3];
  const float* a1     = (const float*)d_in[4];
  const float* a2     = (const float*)d_in[5];
  float* out = (float*)d_out;

  // workspace: hwT (bf16, BN*DD) | t1 | t2 | pacc[nsplit] | pden[nsplit]
  unsigned short* hwT = (unsigned short*)d_ws;
  float* t1 = (float*)(hwT + (size_t)BN * DD);
  float* t2 = t1 + BN;
  float* pacc = t2 + BN;

  int nsplit = 2;
  {
    size_t need = (size_t)BN * DD * 2 + sizeof(float) * (2 * (size_t)BN +
                  (size_t)nsplit * ((size_t)BN * DD + BN));
    if (need > ws_size) nsplit = 1;
  }
  float* pden = pacc + (size_t)nsplit * BN * DD;

  k1_hw_t1_t2<<<BN / 32, 256, 0, stream>>>(h, W, a1, a2, hwT, t1, t2);
  k2_attn<<<nsplit * 256, 256, 0, stream>>>(hwT, adj, t1, t2, pacc, pden, nsplit);
  k3_reduce<<<(BN * DD / 4) / 256, 256, 0, stream>>>(pacc, pden, h, h_root, out,
                                                     nsplit);
}

// Round 4
// 216.103 us; speedup vs baseline: 1.5484x; 1.0298x over previous
//
#include <hip/hip_runtime.h>
#include <hip/hip_bf16.h>

#define BATCH 8
#define NN    2048
#define DD    64
#define BN    (BATCH * NN)          // 16384 rows

#define NSPLIT 4
#define JSPAN  (NN / NSPLIT)        // 512
#define JCHUNK 128
#define CHUNKS (JSPAN / JCHUNK)     // 4
#define HWST   520                  // hws row stride in ushorts (512 + 8 pad)

typedef __attribute__((ext_vector_type(8))) short bf16x8;
typedef __attribute__((ext_vector_type(4))) float f32x4;

// pack two fp32 into one dword of two RNE-rounded bf16 (lo, hi)
static __device__ __forceinline__ unsigned f2bf_pk(float lo, float hi) {
  unsigned ul = __float_as_uint(lo);
  unsigned uh = __float_as_uint(hi);
  ul = (ul + 0x7fffu + ((ul >> 16) & 1u)) >> 16;
  uh = (uh + 0x7fffu + ((uh >> 16) & 1u)) & 0xffff0000u;
  return ul | uh;
}

// -------------------------------------------------------------------------
// Kernel 1: hw = relu(h @ W); t1 = hw@a1; t2 = hw@a2; hwT = bf16 hw^T [b][k][j]
// grid = BN/32 = 512 blocks, 256 threads, 32 rows/block.
// -------------------------------------------------------------------------
__global__ __launch_bounds__(256) void k1_hw_t1_t2(
    const float* __restrict__ h, const float* __restrict__ W,
    const float* __restrict__ a1, const float* __restrict__ a2,
    unsigned short* __restrict__ hwT, float* __restrict__ t1, float* __restrict__ t2) {
  __shared__ float ht[64 * 36];          // h tile transposed [j][i<32], stride 36
  __shared__ float Ws[64 * 64];          // W row-major [j][k]
  __shared__ unsigned short bt[64 * 40]; // bf16 bounce [k][j<32], stride 40

  const int t  = threadIdx.x;
  const int r0 = blockIdx.x * 32;

#pragma unroll
  for (int r = 0; r < 4; ++r) {
    int f = t + 256 * r;
    reinterpret_cast<float4*>(Ws)[f] = reinterpret_cast<const float4*>(W)[f];
  }
#pragma unroll
  for (int r = 0; r < 2; ++r) {
    int f = t + 256 * r;
    int i = f >> 4, j4 = f & 15;
    float4 v = reinterpret_cast<const float4*>(h + (size_t)(r0 + i) * DD)[j4];
    ht[(4 * j4 + 0) * 36 + i] = v.x;
    ht[(4 * j4 + 1) * 36 + i] = v.y;
    ht[(4 * j4 + 2) * 36 + i] = v.z;
    ht[(4 * j4 + 3) * 36 + i] = v.w;
  }
  __syncthreads();

  const int trow = t >> 4, kcol = t & 15;
  float4 acc0 = make_float4(0.f, 0.f, 0.f, 0.f);
  float4 acc1 = make_float4(0.f, 0.f, 0.f, 0.f);

#pragma unroll 8
  for (int j = 0; j < 64; ++j) {
    float2 hv = *reinterpret_cast<const float2*>(&ht[j * 36 + 2 * trow]);
    float4 wv = reinterpret_cast<const float4*>(Ws)[j * 16 + kcol];
    acc0.x = fmaf(hv.x, wv.x, acc0.x); acc0.y = fmaf(hv.x, wv.y, acc0.y);
    acc0.z = fmaf(hv.x, wv.z, acc0.z); acc0.w = fmaf(hv.x, wv.w, acc0.w);
    acc1.x = fmaf(hv.y, wv.x, acc1.x); acc1.y = fmaf(hv.y, wv.y, acc1.y);
    acc1.z = fmaf(hv.y, wv.z, acc1.z); acc1.w = fmaf(hv.y, wv.w, acc1.w);
  }

  acc0.x = fmaxf(acc0.x, 0.f); acc0.y = fmaxf(acc0.y, 0.f);
  acc0.z = fmaxf(acc0.z, 0.f); acc0.w = fmaxf(acc0.w, 0.f);
  acc1.x = fmaxf(acc1.x, 0.f); acc1.y = fmaxf(acc1.y, 0.f);
  acc1.z = fmaxf(acc1.z, 0.f); acc1.w = fmaxf(acc1.w, 0.f);

  float4 a1v = reinterpret_cast<const float4*>(a1)[kcol];
  float4 a2v = reinterpret_cast<const float4*>(a2)[kcol];
  float s1_0 = acc0.x * a1v.x + acc0.y * a1v.y + acc0.z * a1v.z + acc0.w * a1v.w;
  float s1_1 = acc1.x * a1v.x + acc1.y * a1v.y + acc1.z * a1v.z + acc1.w * a1v.w;
  float s2_0 = acc0.x * a2v.x + acc0.y * a2v.y + acc0.z * a2v.z + acc0.w * a2v.w;
  float s2_1 = acc1.x * a2v.x + acc1.y * a2v.y + acc1.z * a2v.z + acc1.w * a2v.w;
#pragma unroll
  for (int m = 1; m <= 8; m <<= 1) {
    s1_0 += __shfl_xor(s1_0, m, 64);
    s1_1 += __shfl_xor(s1_1, m, 64);
    s2_0 += __shfl_xor(s2_0, m, 64);
    s2_1 += __shfl_xor(s2_1, m, 64);
  }
  {
    int row = r0 + 2 * trow;
    if (kcol == 0) {
      t1[row] = s1_0; t1[row + 1] = s1_1;
      t2[row] = s2_0; t2[row + 1] = s2_1;
    }
  }

  {
    const float* a0 = &acc0.x;
    const float* a1p = &acc1.x;
#pragma unroll
    for (int c = 0; c < 4; ++c) {
      int k = 4 * kcol + c;
      *reinterpret_cast<unsigned*>(&bt[k * 40 + 2 * trow]) = f2bf_pk(a0[c], a1p[c]);
    }
  }
  __syncthreads();
  {
    int k = t >> 2, jp = t & 3;
    int bb = r0 >> 11;          // batch
    int jb = r0 & (NN - 1);     // j base within batch
    *reinterpret_cast<int4*>(hwT + ((size_t)bb * DD + k) * NN + jb + jp * 8) =
        *reinterpret_cast<const int4*>(&bt[k * 40 + jp * 8]);
  }
}

// -------------------------------------------------------------------------
// Kernel 2: barrier-free MFMA attention.
// hws (64 k-rows x 512 j bf16) staged ONCE per block; t2 staged once.
// K-loop: adj double-buffered in registers one chunk ahead, no __syncthreads.
// P generated in registers in A-frag layout: lane m owns row i=i0+w*16+m,
// quad owns j=quad*8(+ks*32+c*128);  p = adj ? exp(relu(t1_i+t2_j)) : 1.
// grid = NSPLIT*256 = 1024 blocks (one (split,b,i-tile) each), 256 threads.
// -------------------------------------------------------------------------
__global__ __launch_bounds__(256, 2) void k2_attn(
    const unsigned short* __restrict__ hwT, const int* __restrict__ adj,
    const float* __restrict__ t1, const float* __restrict__ t2,
    float* __restrict__ pacc, float* __restrict__ pden) {
  __shared__ unsigned short hws[64 * HWST];  // 66.6 KB (reused as fp32 bounce)
  __shared__ float t2s[JSPAN];

  const int t     = threadIdx.x;
  const int split = blockIdx.x >> 8;
  const int rem   = blockIdx.x & 255;
  const int b     = rem >> 5;
  const int i0    = (rem & 31) * 64;
  const int w     = t >> 6;
  const int lane  = t & 63;
  const int m     = lane & 15;
  const int quad  = lane >> 4;
  const int jbase = split * JSPAN;

  // one-shot stage: hws[k][j] = hwT[b][k][jbase+j]  (fully coalesced 1KB/wave)
  const unsigned short* hwTb = hwT + (size_t)b * DD * NN + jbase;
#pragma unroll
  for (int r = 0; r < 16; ++r) {
    int idx = t + 256 * r, k = idx >> 6, jp = idx & 63;
    *reinterpret_cast<int4*>(&hws[k * HWST + jp * 8]) =
        *reinterpret_cast<const int4*>(hwTb + (size_t)k * NN + jp * 8);
  }
  if (t < JSPAN / 4)
    *reinterpret_cast<float4*>(&t2s[t * 4]) =
        *reinterpret_cast<const float4*>(t2 + b * NN + jbase + t * 4);

  const float t1v = t1[b * NN + i0 + w * 16 + m];
  const int* adjl = adj + (size_t)(b * NN + i0 + w * 16 + m) * NN + jbase + quad * 8;

  f32x4 acc[4];
#pragma unroll
  for (int g = 0; g < 4; ++g) acc[g] = (f32x4){0.f, 0.f, 0.f, 0.f};
  float den = 0.f;

  int4 adjv[8], adjn[8];
  auto load_adj = [&](int c, int4* dst) {
    const int* ap = adjl + c * JCHUNK;
#pragma unroll
    for (int ks = 0; ks < 4; ++ks) {
      dst[2 * ks]     = *reinterpret_cast<const int4*>(ap + ks * 32);
      dst[2 * ks + 1] = *reinterpret_cast<const int4*>(ap + ks * 32 + 4);
    }
  };

  load_adj(0, adjv);
  __syncthreads();   // hws + t2s ready (the ONLY barrier before the epilogue)

#pragma unroll
  for (int c = 0; c < CHUNKS; ++c) {
    if (c + 1 < CHUNKS) load_adj(c + 1, adjn);

#pragma unroll
    for (int ks = 0; ks < 4; ++ks) {
      const float* t2p = &t2s[c * JCHUNK + ks * 32 + quad * 8];
      float4 e0 = *reinterpret_cast<const float4*>(t2p);
      float4 e1 = *reinterpret_cast<const float4*>(t2p + 4);
      int4 A0 = adjv[2 * ks], A1 = adjv[2 * ks + 1];
      float p0 = (A0.x > 0) ? __expf(fmaxf(t1v + e0.x, 0.f)) : 1.f;
      float p1 = (A0.y > 0) ? __expf(fmaxf(t1v + e0.y, 0.f)) : 1.f;
      float p2 = (A0.z > 0) ? __expf(fmaxf(t1v + e0.z, 0.f)) : 1.f;
      float p3 = (A0.w > 0) ? __expf(fmaxf(t1v + e0.w, 0.f)) : 1.f;
      float p4 = (A1.x > 0) ? __expf(fmaxf(t1v + e1.x, 0.f)) : 1.f;
      float p5 = (A1.y > 0) ? __expf(fmaxf(t1v + e1.y, 0.f)) : 1.f;
      float p6 = (A1.z > 0) ? __expf(fmaxf(t1v + e1.z, 0.f)) : 1.f;
      float p7 = (A1.w > 0) ? __expf(fmaxf(t1v + e1.w, 0.f)) : 1.f;
      den += ((p0 + p1) + (p2 + p3)) + ((p4 + p5) + (p6 + p7));

      union { bf16x8 v; unsigned u[4]; } Af;
      Af.u[0] = f2bf_pk(p0, p1);
      Af.u[1] = f2bf_pk(p2, p3);
      Af.u[2] = f2bf_pk(p4, p5);
      Af.u[3] = f2bf_pk(p6, p7);

#pragma unroll
      for (int g = 0; g < 4; ++g) {
        bf16x8 Bf = *reinterpret_cast<const bf16x8*>(
            &hws[(g * 16 + m) * HWST + c * JCHUNK + ks * 32 + quad * 8]);
        acc[g] = __builtin_amdgcn_mfma_f32_16x16x32_bf16(Af.v, Bf, acc[g], 0, 0, 0);
      }
    }

    if (c + 1 < CHUNKS) {
#pragma unroll
      for (int r = 0; r < 8; ++r) adjv[r] = adjn[r];
    }
  }

  // den: each quad summed its own j subset -> reduce over quads
  den += __shfl_xor(den, 16, 64);
  den += __shfl_xor(den, 32, 64);

  const size_t sbase = (size_t)split * BN + (size_t)b * NN + i0;
  if (quad == 0) pden[sbase + w * 16 + m] = den;

  // coalesced pacc write via LDS bounce (reuse hws as fp32 [64][68])
  __syncthreads();
  float* os = reinterpret_cast<float*>(hws);
#pragma unroll
  for (int g = 0; g < 4; ++g)
#pragma unroll
    for (int r = 0; r < 4; ++r)
      os[(w * 16 + quad * 4 + r) * 68 + g * 16 + m] = acc[g][r];
  __syncthreads();
#pragma unroll
  for (int r2 = 0; r2 < 4; ++r2) {
    int idx = t + 256 * r2, row = idx >> 4, c4 = idx & 15;
    *reinterpret_cast<float4*>(&pacc[(sbase + row) * DD + c4 * 4]) =
        *reinterpret_cast<const float4*>(&os[row * 68 + c4 * 4]);
  }
}

// -------------------------------------------------------------------------
// Kernel 3: reduce partials + normalize + root-select + store.
// -------------------------------------------------------------------------
__global__ __launch_bounds__(256) void k3_reduce(
    const float* __restrict__ pacc, const float* __restrict__ pden,
    const float* __restrict__ h, const float* __restrict__ h_root,
    float* __restrict__ out) {
  const int g   = blockIdx.x * 256 + threadIdx.x;  // float4 index
  const int row = g >> 4;
  const int k4  = g & 15;

  float4 a = make_float4(0.f, 0.f, 0.f, 0.f);
  float den = 0.f;
#pragma unroll
  for (int s = 0; s < NSPLIT; ++s) {
    const size_t prow = (size_t)s * BN + row;
    float4 p = reinterpret_cast<const float4*>(pacc + prow * DD)[k4];
    a.x += p.x; a.y += p.y; a.z += p.z; a.w += p.w;
    den += pden[prow];
  }
  const float hr = h_root[row];
  float4 res;
  if (hr > 0.f) {
    const float inv = 1.f / den;
    res.x = a.x * inv; res.y = a.y * inv; res.z = a.z * inv; res.w = a.w * inv;
  } else {
    res = reinterpret_cast<const float4*>(h)[g];
  }
  reinterpret_cast<float4*>(out)[g] = res;
}

extern "C" void kernel_launch(void* const* d_in, const int* in_sizes, int n_in,
                              void* d_out, int out_size, void* d_ws, size_t ws_size,
                              hipStream_t stream) {
  const float* h      = (const float*)d_in[0];
  const int*   adj    = (const int*)d_in[1];
  const float* h_root = (const float*)d_in[2];
  const float* W      = (const float*)d_in[3];
  const float* a1     = (const float*)d_in[4];
  const float* a2     = (const float*)d_in[5];
  float* out = (float*)d_out;

  // workspace: hwT (bf16, BN*DD) | t1 | t2 | pacc[NSPLIT] | pden[NSPLIT]
  unsigned short* hwT = (unsigned short*)d_ws;
  float* t1 = (float*)(hwT + (size_t)BN * DD);
  float* t2 = t1 + BN;
  float* pacc = t2 + BN;
  float* pden = pacc + (size_t)NSPLIT * BN * DD;

  k1_hw_t1_t2<<<BN / 32, 256, 0, stream>>>(h, W, a1, a2, hwT, t1, t2);
  k2_attn<<<NSPLIT * 256, 256, 0, stream>>>(hwT, adj, t1, t2, pacc, pden);
  k3_reduce<<<(BN * DD / 4) / 256, 256, 0, stream>>>(pacc, pden, h, h_root, out);
}